// Round 2
// baseline (831.194 us; speedup 1.0000x reference)
//
#include <hip/hip_runtime.h>
#include <math.h>

typedef unsigned int   uint32;
typedef unsigned short ushort16;
typedef __attribute__((ext_vector_type(8))) short  short8;   // 8 bf16 (MFMA A/B frag)
typedef __attribute__((ext_vector_type(4))) float  floatx4;  // MFMA C/D frag

// Problem dims
#define Bb   512
#define QLn  128
#define ALn  512
#define En   300
#define Fn   400
#define OW   416      // packed output width: 400 real + 16 zero (832 B = 13*64)
#define EPAD 320      // e padded 300 -> 320 per shift; K_total = 3*320 = 960
#define NV   50001

typedef const __attribute__((address_space(1))) unsigned int guint_t;
typedef __attribute__((address_space(3))) unsigned int luint_t;
#define GLDS16(g, l) __builtin_amdgcn_global_load_lds((guint_t*)(g), (luint_t*)(l), 16, 0, 0)

static __device__ __forceinline__ float bf_lo(uint32 u) { return __uint_as_float(u << 16); }
static __device__ __forceinline__ float bf_hi(uint32 u) { return __uint_as_float(u & 0xffff0000u); }
static __device__ __forceinline__ ushort16 f2bf(float f) {
    uint32 u = __float_as_uint(f);
    uint32 r = (u + 0x7fffu + ((u >> 16) & 1u)) >> 16;   // RNE
    return (ushort16)r;
}
static __device__ __forceinline__ uint32 pack2(float a, float b) {
    return (uint32)f2bf(a) | ((uint32)f2bf(b) << 16);
}

// ---------------------------------------------------------------------------
// embcvt: embbf[v][0..320) = bf16(emb[v][0..300)), e>=300 zero.
// ---------------------------------------------------------------------------
__global__ __launch_bounds__(128) void embcvt_kernel(
        const float* __restrict__ emb, char* __restrict__ embbf)
{
    const int r = blockIdx.x, j = threadIdx.x;
    const float* er = emb + (size_t)r * En;
    uint32* orow = (uint32*)(embbf + (size_t)r * 640);
    for (int d = j; d < 160; d += 128) {
        uint32 v = 0;
        if (d < 150) {
            float2 f2v = *(const float2*)(er + 2 * d);
            v = pack2(f2v.x, f2v.y);
        }
        orow[d] = v;
    }
}

// ---------------------------------------------------------------------------
// prep_wt: Wt2[f][p] = W[f][e*3+kk] (p = kk*320+e), bf16, zero pad; bias2.
// ---------------------------------------------------------------------------
__global__ __launch_bounds__(256) void prep_wt(
        const float* __restrict__ W, const float* __restrict__ cb,
        ushort16* __restrict__ Wt2, float* __restrict__ bias2)
{
    const int f = blockIdx.x, t = threadIdx.x;
    for (int p2 = t; p2 < 480; p2 += 256) {
        int p = 2 * p2;
        float v0 = 0.f, v1 = 0.f;
        if (f < Fn) {
            int kk = p / EPAD, e = p - kk * EPAD;
            if (e < En)     v0 = W[(size_t)f * 900 + e * 3 + kk];
            if (e + 1 < En) v1 = W[(size_t)f * 900 + (e + 1) * 3 + kk];
        }
        *(uint32*)&Wt2[(size_t)f * 960 + p] = pack2(v0, v1);
    }
    if (t == 0) bias2[f] = (f < Fn) ? cb[f] : 0.f;
}

// ---------------------------------------------------------------------------
// prep_wp: Wp2[g][p] = sum_f U[f][g]*W[f][p900], fp32 accum, bf16 store.
// ---------------------------------------------------------------------------
__global__ __launch_bounds__(256) void prep_wp(
        const float* __restrict__ W, const float* __restrict__ U,
        ushort16* __restrict__ Wp2)
{
    __shared__ float Wl[400 * 32];   // 51.2 KB
    const int t = threadIdx.x;
    const int pc = blockIdx.x, gc = blockIdx.y;
    const int kk = (pc * 32) / EPAD, e0 = pc * 32 - kk * EPAD;

    for (int i = t; i < 400 * 32; i += 256) {
        int f = i >> 5, j = i & 31, e = e0 + j;
        Wl[i] = (e < En) ? W[(size_t)f * 900 + e * 3 + kk] : 0.f;
    }
    __syncthreads();

    const int g = gc * 128 + (t >> 1);
    const int jh = (t & 1) * 16;
    float acc[16];
#pragma unroll
    for (int k = 0; k < 16; ++k) acc[k] = 0.f;

    for (int f = 0; f < Fn; ++f) {
        float uf = 0.f;
        if (g < Fn) uf = U[(size_t)f * Fn + g];
        const float* wl = Wl + f * 32 + jh;
#pragma unroll
        for (int k = 0; k < 16; ++k) acc[k] = fmaf(uf, wl[k], acc[k]);
    }
    ushort16* orow = Wp2 + (size_t)g * 960 + pc * 32 + jh;
#pragma unroll
    for (int k = 0; k < 16; k += 2)
        *(uint32*)&orow[k] = pack2(acc[k], acc[k + 1]);
}

// prep_bp: bp2[g] = sum_f U[f][g]*cb[f] (g<512, zero beyond 400)
__global__ __launch_bounds__(256) void prep_bp(
        const float* __restrict__ cb, const float* __restrict__ U,
        float* __restrict__ bp2)
{
    __shared__ float cbl[Fn];
    const int t = threadIdx.x;
    for (int f = t; f < Fn; f += 256) cbl[f] = cb[f];
    __syncthreads();
#pragma unroll
    for (int h = 0; h < 2; ++h) {
        int g = t + h * 256;
        float s = 0.f;
        if (g < Fn)
            for (int f = 0; f < Fn; ++f) s += cbl[f] * U[(size_t)f * Fn + g];
        bp2[g] = s;
    }
}

// ---------------------------------------------------------------------------
// conv_tile256: 256-row x (main 256 / tail 160)-col tile, 8 waves, 512 thr.
// Wave grid NWM x NWN; MF x NF 16x16 frags per wave. BROWS = B rows staged.
// Rows split into two 128-row segments (seg = row>>7) so one tile can cover
// either 256 contiguous A-rows or a PAIR of 128-row Q batches.
//   - tok for row r, shift kk: idx = (r&127)+kk-1; valid iff idx in
//     [vlo_seg, vhi_seg); token from tp_seg[idx]; else tok 0 (embbf row 0=0).
//   - stores: obSeg = seg? ob1 : ob0 (ob1 may be null -> skip).
// 2-phase dbuf: STAGE(nxt) right after barrier, consume cur, 1 barrier/step.
// Chunk-permutation swizzle (cg/chunkOff) identical to the verified 128-tile
// scheme; all staging groups stay 16-row aligned so the slot invariant holds.
// Line-traffic rationale: 256^2 tile = 8.2 KFLOP per 64B line vs 3.9 at 128^2.
// ---------------------------------------------------------------------------
template<int NWM, int NWN, int MF, int NF, int BROWS>
static __device__ __forceinline__ void conv_tile256(
        const int* __restrict__ tp0, const int* __restrict__ tp1,
        int vlo0, int vhi0, int vlo1, int vhi1,
        const char* __restrict__ embbf,
        const char* __restrict__ WB,     // weight base already offset to colOff
        const float* __restrict__ biasv, int colOff,
        ushort16* __restrict__ ob0, ushort16* __restrict__ ob1,
        char* As, char* Bs)
{
    const int t = threadIdx.x, lane = t & 63, w = t >> 6;
    const int wr = w / NWN, wc = w % NWN;
    const int fm = lane & 15;
    const int cg = ((lane & 3) - ((lane >> 3) & 3)) & 3;
    const int rl = lane >> 2;
    const int chunkOff = (((lane >> 4) + (fm >> 1)) & 3) * 16;

    // A gather: wave w stages rows w*32 + i*16 + rl, i in {0,1}
    const char* srcA[3][2];
#pragma unroll
    for (int kk = 0; kk < 3; ++kk)
#pragma unroll
        for (int i = 0; i < 2; ++i) {
            const int r = w * 32 + i * 16 + rl;
            const int seg = r >> 7, p = r & 127;
            const int idx = p + kk - 1;
            const int* tp = seg ? tp1 : tp0;
            const int lo = seg ? vlo1 : vlo0, hi = seg ? vhi1 : vhi0;
            const int tok = (idx >= lo && idx < hi) ? tp[idx] : 0;
            srcA[kk][i] = embbf + (size_t)tok * 640 + cg * 16;
        }
    const char* srcB0; const char* srcB1;
    if (BROWS == 256) {
        srcB0 = WB + (size_t)(w * 32 + rl) * 1920 + cg * 16;
        srcB1 = srcB0 + (size_t)16 * 1920;
    } else {
        srcB0 = WB + (size_t)(w * 16 + rl) * 1920 + cg * 16;
        srcB1 = WB + (size_t)(128 + w * 16 + rl) * 1920 + cg * 16;
    }
    char* AsW = As + w * 2048;
    char* BsW0; char* BsW1;
    if (BROWS == 256) { BsW0 = Bs + w * 2048; BsW1 = BsW0 + 1024; }
    else              { BsW0 = Bs + w * 1024; BsW1 = Bs + 8192 + w * 1024; }

    floatx4 acc[MF][NF];
    const floatx4 zz = {0.f, 0.f, 0.f, 0.f};
#pragma unroll
    for (int m = 0; m < MF; ++m)
#pragma unroll
        for (int n = 0; n < NF; ++n) acc[m][n] = zz;

#define CSTG(kkc, ko, buf) do {                                               \
        const int _ko = (ko); const int _bo = (buf) * 16384;                  \
        GLDS16(srcA[kkc][0] + _ko,              AsW + _bo);                   \
        GLDS16(srcA[kkc][1] + _ko,              AsW + _bo + 1024);            \
        GLDS16(srcB0 + (kkc) * 640 + _ko,       BsW0 + _bo);                  \
        if (BROWS == 256 || w < 2)                                            \
            GLDS16(srcB1 + (kkc) * 640 + _ko,   BsW1 + _bo);                  \
    } while (0)

    int cur = 0;
    CSTG(0, 0, 0);
    __syncthreads();

#pragma unroll
    for (int kk = 0; kk < 3; ++kk) {
        const int kn = (kk < 2) ? kk + 1 : 0;
        for (int ks = 0; ks < 10; ++ks) {
            const int nxt = cur ^ 1;
            if (ks < 9)      CSTG(kk, (ks + 1) * 64, nxt);
            else if (kk < 2) CSTG(kn, 0, nxt);

            short8 af[MF], bfv[NF];
            const char* Ac = As + cur * 16384;
            const char* Bc = Bs + cur * 16384;
#pragma unroll
            for (int m = 0; m < MF; ++m)
                af[m] = *(const short8*)(Ac + (wr * (MF * 16) + m * 16 + fm) * 64 + chunkOff);
#pragma unroll
            for (int n = 0; n < NF; ++n)
                bfv[n] = *(const short8*)(Bc + (wc * (NF * 16) + n * 16 + fm) * 64 + chunkOff);
            __builtin_amdgcn_s_setprio(1);
#pragma unroll
            for (int m = 0; m < MF; ++m)
#pragma unroll
                for (int n = 0; n < NF; ++n)
                    acc[m][n] = __builtin_amdgcn_mfma_f32_16x16x32_bf16(
                        af[m], bfv[n], acc[m][n], 0, 0, 0);
            __builtin_amdgcn_s_setprio(0);
            __syncthreads();
            cur = nxt;
        }
    }
#undef CSTG

    float bn[NF];
#pragma unroll
    for (int n = 0; n < NF; ++n) bn[n] = biasv[colOff + wc * (NF * 16) + n * 16 + fm];
#pragma unroll
    for (int m = 0; m < MF; ++m) {
        const int rowg0 = wr * (MF * 16) + m * 16 + ((lane >> 4) * 4);
        const int seg = rowg0 >> 7;          // constant over r (4-row group)
        ushort16* ob = seg ? ob1 : ob0;
        if (!ob) continue;
        const int rloc = rowg0 & 127;
#pragma unroll
        for (int n = 0; n < NF; ++n) {
            const int col = colOff + wc * (NF * 16) + n * 16 + fm;
#pragma unroll
            for (int r = 0; r < 4; ++r)
                ob[(size_t)(rloc + r) * OW + col] = f2bf(acc[m][n][r] + bn[n]);
        }
    }
}

// Merged conv dispatch, 512 threads.
// Region A (bx < nbA): A-conv, idx -> (nt, mt, b); tile rows b*512+mt*256.
// Region Q: idx -> (nt, wsel, pair); tile rows = batches 2P, 2P+1.
__global__ __launch_bounds__(512) void conv_all(
        const int* __restrict__ question, const int* __restrict__ answer,
        const char* __restrict__ embbf,
        const char* __restrict__ Wt2, const char* __restrict__ Wp2,
        const float* __restrict__ bias2, const float* __restrict__ bp2,
        ushort16* __restrict__ qb, ushort16* __restrict__ qpb,
        ushort16* __restrict__ ab, int nb, int nbA)
{
    __shared__ __align__(16) char As[32768];   // 2 bufs x 256 rows x 64B
    __shared__ __align__(16) char Bs[32768];   // 2 bufs x <=256 rows x 64B
    int bx = blockIdx.x;
    if (bx < nbA) {
        const int nt = bx & 1, mt = (bx >> 1) & 1, b = bx >> 2;
        const int l0 = mt * 256;
        const int* tp0 = answer + (size_t)b * ALn + l0;
        const int* tp1 = tp0 + 128;
        const int vlo0 = -l0,         vhi0 = ALn - l0;
        const int vlo1 = -(l0 + 128), vhi1 = ALn - l0 - 128;
        ushort16* ob0 = ab + ((size_t)b * ALn + l0) * OW;
        ushort16* ob1 = ob0 + (size_t)128 * OW;
        if (nt == 0)
            conv_tile256<2, 4, 8, 4, 256>(tp0, tp1, vlo0, vhi0, vlo1, vhi1,
                embbf, Wt2, bias2, 0, ob0, ob1, As, Bs);
        else
            conv_tile256<4, 2, 4, 5, 160>(tp0, tp1, vlo0, vhi0, vlo1, vhi1,
                embbf, Wt2 + (size_t)256 * 1920, bias2, 256, ob0, ob1, As, Bs);
    } else {
        const int i = bx - nbA;
        const int nt = i & 1, ws = (i >> 1) & 1, P = i >> 2;
        const int T = 2 * P;
        const bool v1 = (T + 1) < nb;
        const int* tp0 = question + (size_t)T * QLn;
        const int* tp1 = v1 ? tp0 + QLn : tp0;
        const int vhi1 = v1 ? QLn : 0;
        ushort16* obase = ws ? qpb : qb;
        ushort16* ob0 = obase + (size_t)T * QLn * OW;
        ushort16* ob1 = v1 ? ob0 + (size_t)QLn * OW : (ushort16*)0;
        const char*  Wsel = ws ? Wp2 : Wt2;
        const float* bsel = ws ? bp2 : bias2;
        if (nt == 0)
            conv_tile256<2, 4, 8, 4, 256>(tp0, tp1, 0, QLn, 0, vhi1,
                embbf, Wsel, bsel, 0, ob0, ob1, As, Bs);
        else
            conv_tile256<4, 2, 4, 5, 160>(tp0, tp1, 0, QLn, 0, vhi1,
                embbf, Wsel + (size_t)256 * 1920, bsel, 256, ob0, ob1, As, Bs);
    }
}

// ---------------------------------------------------------------------------
// fused_g: block (b, a-chunk c). Gpre = Q' A^T (K=416, cols 400..416 zeros).
// Double-buffered 2-phase pipeline, single barrier per K-step.
// ---------------------------------------------------------------------------
__global__ __launch_bounds__(256) void fused_g(
        const ushort16* __restrict__ Qp,   // [nb][128][416]
        const ushort16* __restrict__ Av,   // [nb][512][416]
        float* __restrict__ rowPart,       // [nb][4][128]
        float* __restrict__ colMg,         // [nb][512]
        int nb)
{
    __shared__ __align__(16) char Qs[16384];    // 2 x 8192 (dbuf)
    __shared__ __align__(16) char Asl[16384];   // 2 x 8192 (dbuf)
    __shared__ float rowM2[128][2];
    __shared__ float colM2[128][2];

    const int t = threadIdx.x, lane = t & 63, w = t >> 6;
    const int bx = blockIdx.x;
    const int xcd = bx & 7, rest = bx >> 3;
    const int c = rest & 3, g = rest >> 2;
    const int T = g * 8 + xcd;
    if (T >= nb) return;
    const int b = T;
    const int wr = w >> 1, wc = w & 1;
    const int fm = lane & 15;
    const int cg = ((lane & 3) - ((lane >> 3) & 3)) & 3;
    const int srow = w * 16 + (lane >> 2);
    const int chunkOff = (((lane >> 4) + (fm >> 1)) & 3) * 16;

    const char* Qpb = (const char*)Qp + (size_t)b * 106496;
    const char* Ab  = (const char*)Av + (size_t)b * 425984 + (size_t)c * 106496;
    const char* srcQ = Qpb + (size_t)srow * 832 + cg * 16;
    const char* srcA = Ab  + (size_t)srow * 832 + cg * 16;
    char* QsW = Qs + w * 1024;
    char* AsW = Asl + w * 1024;

    floatx4 acc[4][4];
    const floatx4 zz = {0.f, 0.f, 0.f, 0.f};
#pragma unroll
    for (int m = 0; m < 4; ++m)
#pragma unroll
        for (int n = 0; n < 4; ++n) acc[m][n] = zz;

#define GSTAGE(colb, buf) do {                                                \
        const int _c = (colb); const int _o = (buf) * 8192;                   \
        GLDS16(srcQ + _c,         QsW + _o);                                  \
        GLDS16(srcQ + 53248 + _c, QsW + _o + 4096);                           \
        GLDS16(srcA + _c,         AsW + _o);                                  \
        GLDS16(srcA + 53248 + _c, AsW + _o + 4096);                           \
    } while (0)

    int cur = 0;
    GSTAGE(0, 0);
    __syncthreads();

    for (int ks = 0; ks < 13; ++ks) {
        const int nxt = cur ^ 1;
        if (ks < 12) GSTAGE((ks + 1) * 64, nxt);

        short8 qa[4], aa_[4];
        const char* Qc = Qs + cur * 8192;
        const char* Ac = Asl + cur * 8192;
#pragma unroll
        for (int m = 0; m < 4; ++m)
            qa[m] = *(const short8*)(Qc + (wr * 64 + m * 16 + fm) * 64 + chunkOff);
#pragma unroll
        for (int n = 0; n < 4; ++n)
            aa_[n] = *(const short8*)(Ac + (wc * 64 + n * 16 + fm) * 64 + chunkOff);
        __builtin_amdgcn_s_setprio(1);
#pragma unroll
        for (int m = 0; m < 4; ++m)
#pragma unroll
            for (int n = 0; n < 4; ++n)
                acc[m][n] = __builtin_amdgcn_mfma_f32_16x16x32_bf16(
                    qa[m], aa_[n], acc[m][n], 0, 0, 0);
        __builtin_amdgcn_s_setprio(0);
        __syncthreads();
        cur = nxt;
    }
#undef GSTAGE

#pragma unroll
    for (int m = 0; m < 4; ++m)
#pragma unroll
        for (int r = 0; r < 4; ++r) {
            float v = fmaxf(fmaxf(acc[m][0][r], acc[m][1][r]),
                            fmaxf(acc[m][2][r], acc[m][3][r]));
            v = fmaxf(v, __shfl_xor(v, 1));
            v = fmaxf(v, __shfl_xor(v, 2));
            v = fmaxf(v, __shfl_xor(v, 4));
            v = fmaxf(v, __shfl_xor(v, 8));
            if (fm == 0) rowM2[wr * 64 + m * 16 + (lane >> 4) * 4 + r][wc] = v;
        }
#pragma unroll
    for (int n = 0; n < 4; ++n) {
        float v = -1e30f;
#pragma unroll
        for (int m = 0; m < 4; ++m)
#pragma unroll
            for (int r = 0; r < 4; ++r) v = fmaxf(v, acc[m][n][r]);
        v = fmaxf(v, __shfl_xor(v, 16));
        v = fmaxf(v, __shfl_xor(v, 32));
        if (lane < 16) colM2[wc * 64 + n * 16 + lane][wr] = v;
    }
    __syncthreads();
    if (t < 128) {
        rowPart[((size_t)b * 4 + c) * 128 + t] = fmaxf(rowM2[t][0], rowM2[t][1]);
        colMg[(size_t)b * 512 + c * 128 + t]   = fmaxf(colM2[t][0], colM2[t][1]);
    }
}

// ---------------------------------------------------------------------------
// fused_pool: per-batch softmax over tanh(maxes) + pooling + cosine.
// ---------------------------------------------------------------------------
static __device__ __forceinline__ float block_reduce_max(float v, volatile float* red) {
    int t = threadIdx.x;
    red[t] = v; __syncthreads();
    for (int s = 128; s > 0; s >>= 1) {
        if (t < s) red[t] = fmaxf(red[t], red[t + s]);
        __syncthreads();
    }
    float r = red[0]; __syncthreads();
    return r;
}
static __device__ __forceinline__ float block_reduce_sum(float v, volatile float* red) {
    int t = threadIdx.x;
    red[t] = v; __syncthreads();
    for (int s = 128; s > 0; s >>= 1) {
        if (t < s) red[t] = red[t] + red[t + s];
        __syncthreads();
    }
    float r = red[0]; __syncthreads();
    return r;
}

__global__ __launch_bounds__(256) void fused_pool(
        const ushort16* __restrict__ Qv,   // [nb][128][416]
        const ushort16* __restrict__ Av,   // [nb][512][416]
        const float* __restrict__ rowPart, // [nb][4][128]
        const float* __restrict__ colMg,   // [nb][512]
        float* __restrict__ out)
{
    __shared__ float colv[ALn];
    __shared__ float roq[QLn];
    __shared__ float red[256];
    const int t = threadIdx.x, b = blockIdx.x;

    float v = -1e30f;
    if (t < QLn) {
        const float* rp = rowPart + (size_t)b * 512;
        float rm = fmaxf(fmaxf(rp[t], rp[128 + t]), fmaxf(rp[256 + t], rp[384 + t]));
        v = tanhf(rm);
    }
    float vmax = block_reduce_max(v, red);
    float ex = (t < QLn) ? __expf(v - vmax) : 0.f;
    float ssum = block_reduce_sum(ex, red);
    if (t < QLn) roq[t] = ex / ssum;

    float c0 = tanhf(colMg[(size_t)b * 512 + t]);
    float c1 = tanhf(colMg[(size_t)b * 512 + 256 + t]);
    float cmax = block_reduce_max(fmaxf(c0, c1), red);
    float e0 = __expf(c0 - cmax), e1 = __expf(c1 - cmax);
    float csum = block_reduce_sum(e0 + e1, red);
    colv[t] = e0 / csum;
    colv[t + 256] = e1 / csum;
    __syncthreads();

    float rq0 = 0.f, rq1 = 0.f, ra0 = 0.f, ra1 = 0.f;
    if (t < 208) {
        const uint32* Qb32 = (const uint32*)((const char*)Qv + (size_t)b * 106496);
#pragma unroll 4
        for (int q = 0; q < QLn; ++q) {
            float wv = roq[q];
            uint32 u = Qb32[q * 208 + t];
            rq0 = fmaf(bf_lo(u), wv, rq0);
            rq1 = fmaf(bf_hi(u), wv, rq1);
        }
        const uint32* Ab32 = (const uint32*)((const char*)Av + (size_t)b * 425984);
#pragma unroll 4
        for (int a = 0; a < ALn; ++a) {
            float wv = colv[a];
            uint32 u = Ab32[a * 208 + t];
            ra0 = fmaf(bf_lo(u), wv, ra0);
            ra1 = fmaf(bf_hi(u), wv, ra1);
        }
    }

    float dd  = block_reduce_sum(rq0 * ra0 + rq1 * ra1, red);
    float qq  = block_reduce_sum(rq0 * rq0 + rq1 * rq1, red);
    float aam = block_reduce_sum(ra0 * ra0 + ra1 * ra1, red);
    if (t == 0) {
        float nq = fmaxf(sqrtf(qq), 1e-8f);
        float na = fmaxf(sqrtf(aam), 1e-8f);
        out[b] = dd / (nq * na);
    }
}

// ---------------------------------------------------------------------------
// launch — ws_size-adaptive balanced batch chunking (pure function of ws_size)
// ws: [Wt2 | Wp2 | bias2 | bp2 | embbf | per-chunk: qb qpb ab rowP colM]
// ---------------------------------------------------------------------------
extern "C" void kernel_launch(void* const* d_in, const int* in_sizes, int n_in,
                              void* d_out, int out_size, void* d_ws, size_t ws_size,
                              hipStream_t stream)
{
    const int*   question = (const int*)d_in[0];
    const int*   answer   = (const int*)d_in[1];
    const float* emb      = (const float*)d_in[2];
    const float* conv_w   = (const float*)d_in[3];
    const float* conv_b   = (const float*)d_in[4];
    const float* U        = (const float*)d_in[5];
    float* out = (float*)d_out;
    char* ws = (char*)d_ws;

    const size_t WT2B   = (size_t)512 * 960 * 2;         // 983,040
    const size_t EMBB   = (size_t)NV * 640;              // 32,000,640
    const size_t FIXED0 = 2 * WT2B + 4096;               // 1,970,176
    const size_t FIXED  = FIXED0 + EMBB;                 // 33,970,816
    const size_t QB     = (size_t)QLn * OW * 2;          // 106,496
    const size_t AB     = (size_t)ALn * OW * 2;          // 425,984
    const size_t MXB    = 4096;
    const size_t PER_B  = 2 * QB + AB + MXB;             // 643,072

    size_t avail = (ws_size > FIXED) ? (ws_size - FIXED) : 0;
    int CB = (int)(avail / PER_B);
    if (CB > Bb) CB = Bb;
    if (CB < 1)  CB = 1;
    int nch = (Bb + CB - 1) / CB;
    int CBe = (Bb + nch - 1) / nch;      // balanced chunk size (<= CB)

    char*  wt2   = ws;
    char*  wp2   = ws + WT2B;
    float* bias2 = (float*)(ws + 2 * WT2B);
    float* bp2   = (float*)(ws + 2 * WT2B + 2048);
    char*  embbf = ws + FIXED0;
    char*  qb    = ws + FIXED;
    char*  qpb   = qb  + (size_t)CB * QB;
    char*  ab    = qpb + (size_t)CB * QB;
    float* rowP  = (float*)(ab + (size_t)CB * AB);
    float* colM  = rowP + (size_t)CB * 512;

    embcvt_kernel<<<NV, 128, 0, stream>>>(emb, embbf);
    prep_wt<<<512, 256, 0, stream>>>(conv_w, conv_b, (ushort16*)wt2, bias2);
    prep_wp<<<dim3(30, 4), 256, 0, stream>>>(conv_w, U, (ushort16*)wp2);
    prep_bp<<<1, 256, 0, stream>>>(conv_b, U, bp2);

    for (int b0 = 0; b0 < Bb; b0 += CBe) {
        int nb = (Bb - b0 < CBe) ? (Bb - b0) : CBe;
        int nbA = nb * 4;                       // (b, mt, nt)
        int nbQ = ((nb + 1) / 2) * 4;           // (pair, wsel, nt)
        conv_all<<<nbA + nbQ, 512, 0, stream>>>(
            question + (size_t)b0 * QLn, answer + (size_t)b0 * ALn, embbf,
            wt2, wp2, bias2, bp2,
            (ushort16*)qb, (ushort16*)qpb, (ushort16*)ab, nb, nbA);

        int blocksG = ((nb + 7) / 8) * 8 * 4;
        fused_g<<<blocksG, 256, 0, stream>>>((const ushort16*)qpb, (const ushort16*)ab,
                                             rowP, colM, nb);
        fused_pool<<<nb, 256, 0, stream>>>((const ushort16*)qb, (const ushort16*)ab,
                                           rowP, colM, out + b0);
    }
}

// Round 3
// 668.211 us; speedup vs baseline: 1.2439x; 1.2439x over previous
//
#include <hip/hip_runtime.h>
#include <math.h>

typedef unsigned int   uint32;
typedef unsigned short ushort16;
typedef __attribute__((ext_vector_type(8))) short  short8;   // 8 bf16 (MFMA A/B frag)
typedef __attribute__((ext_vector_type(4))) float  floatx4;  // MFMA C/D frag

// Problem dims
#define Bb   512
#define QLn  128
#define ALn  512
#define En   300
#define Fn   400
#define OW   416      // packed output width: 400 real + 16 zero (832 B = 13*64)
#define EPAD 320      // e padded 300 -> 320 per shift
#define NV   50001
#define ECROWS 50176  // 196*256 padded vocab rows
#define ECSTRIDE 2560 // 1280 cols * 2B (3*416 used + 32 pad)

typedef const __attribute__((address_space(1))) unsigned int guint_t;
typedef __attribute__((address_space(3))) unsigned int luint_t;
#define GLDS16(g, l) __builtin_amdgcn_global_load_lds((guint_t*)(g), (luint_t*)(l), 16, 0, 0)

static __device__ __forceinline__ float bf_lo(uint32 u) { return __uint_as_float(u << 16); }
static __device__ __forceinline__ float bf_hi(uint32 u) { return __uint_as_float(u & 0xffff0000u); }
static __device__ __forceinline__ ushort16 f2bf(float f) {
    uint32 u = __float_as_uint(f);
    uint32 r = (u + 0x7fffu + ((u >> 16) & 1u)) >> 16;   // RNE
    return (ushort16)r;
}
static __device__ __forceinline__ uint32 pack2(float a, float b) {
    return (uint32)f2bf(a) | ((uint32)f2bf(b) << 16);
}

// ---------------------------------------------------------------------------
// embcvt: embbf[v][0..320) = bf16(emb[v][0..300)), e>=300 zero.
// ---------------------------------------------------------------------------
__global__ __launch_bounds__(128) void embcvt_kernel(
        const float* __restrict__ emb, char* __restrict__ embbf)
{
    const int r = blockIdx.x, j = threadIdx.x;
    const float* er = emb + (size_t)r * En;
    uint32* orow = (uint32*)(embbf + (size_t)r * 640);
    for (int d = j; d < 160; d += 128) {
        uint32 v = 0;
        if (d < 150) {
            float2 f2v = *(const float2*)(er + 2 * d);
            v = pack2(f2v.x, f2v.y);
        }
        orow[d] = v;
    }
}

// ---------------------------------------------------------------------------
// prep_wt: Wt2[f][p] = W[f][e*3+kk] (p = kk*320+e), bf16, zero pad; bias2.
// Rows f in [400,512) are fully zero (used as zero-rows by ec_gemm pad).
// ---------------------------------------------------------------------------
__global__ __launch_bounds__(256) void prep_wt(
        const float* __restrict__ W, const float* __restrict__ cb,
        ushort16* __restrict__ Wt2, float* __restrict__ bias2)
{
    const int f = blockIdx.x, t = threadIdx.x;
    for (int p2 = t; p2 < 480; p2 += 256) {
        int p = 2 * p2;
        float v0 = 0.f, v1 = 0.f;
        if (f < Fn) {
            int kk = p / EPAD, e = p - kk * EPAD;
            if (e < En)     v0 = W[(size_t)f * 900 + e * 3 + kk];
            if (e + 1 < En) v1 = W[(size_t)f * 900 + (e + 1) * 3 + kk];
        }
        *(uint32*)&Wt2[(size_t)f * 960 + p] = pack2(v0, v1);
    }
    if (t == 0) bias2[f] = (f < Fn) ? cb[f] : 0.f;
}

// ---------------------------------------------------------------------------
// prep_ub: Ub[g][f] = bf16(U[f][g]), [416][416], zero pad both dims.
// ---------------------------------------------------------------------------
__global__ __launch_bounds__(256) void prep_ub(
        const float* __restrict__ U, ushort16* __restrict__ Ub)
{
    const int g = blockIdx.x, t = threadIdx.x;
    uint32* orow = (uint32*)(Ub + (size_t)g * 416);
    for (int f2 = t; f2 < 208; f2 += 256) {
        int f = 2 * f2;
        float v0 = 0.f, v1 = 0.f;
        if (g < Fn) {
            if (f < Fn)     v0 = U[(size_t)f * Fn + g];
            if (f + 1 < Fn) v1 = U[(size_t)(f + 1) * Fn + g];
        }
        orow[f2] = pack2(v0, v1);
    }
}

// ---------------------------------------------------------------------------
// ec_gemm: EC[v][kk*416+f] = sum_e embbf[v][e] * Wt2[f][kk*320+e]  (bf16)
// 256x256 tile, 512 thr, 8 waves (2x4), MF=8 NF=4, K=320 (10 steps of 64B).
// B rows map n -> (kk, f): ptr = Wt2 + f*1920 + kk*640. n>=1248 -> zero row.
// Grid (196, 5). v-rows up to 50175; embbf overrun reads land in chunk region
// (allocated); garbage EC rows beyond 50000 are never gathered.
// ---------------------------------------------------------------------------
__global__ __launch_bounds__(512) void ec_gemm(
        const char* __restrict__ embbf, const char* __restrict__ Wt2,
        char* __restrict__ EC)
{
    __shared__ __align__(16) char As[32768];   // 2 x 256 rows x 64B
    __shared__ __align__(16) char Bs[32768];
    const int t = threadIdx.x, lane = t & 63, w = t >> 6;
    const int v0 = blockIdx.x * 256, c0 = blockIdx.y * 256;
    const int wr = w >> 2, wc = w & 3;
    const int fm = lane & 15;
    const int cg = ((lane & 3) - ((lane >> 3) & 3)) & 3;
    const int rl = lane >> 2;
    const int chunkOff = (((lane >> 4) + (fm >> 1)) & 3) * 16;

    const char* srcA[2];
    const char* srcB[2];
#pragma unroll
    for (int i = 0; i < 2; ++i) {
        srcA[i] = embbf + (size_t)(v0 + w * 32 + i * 16 + rl) * 640 + cg * 16;
        int n = c0 + w * 32 + i * 16 + rl;
        int kk = n / 416, f = n - kk * 416;
        if (n >= 1248) { kk = 0; f = 508; }   // zero row
        srcB[i] = Wt2 + (size_t)f * 1920 + kk * 640 + cg * 16;
    }
    char* AsW = As + w * 2048;
    char* BsW = Bs + w * 2048;

    floatx4 acc[8][4];
    const floatx4 zz = {0.f, 0.f, 0.f, 0.f};
#pragma unroll
    for (int m = 0; m < 8; ++m)
#pragma unroll
        for (int n = 0; n < 4; ++n) acc[m][n] = zz;

#define ESTG(ko, buf) do {                                                    \
        const int _ko = (ko); const int _bo = (buf) * 16384;                  \
        GLDS16(srcA[0] + _ko, AsW + _bo);                                     \
        GLDS16(srcA[1] + _ko, AsW + _bo + 1024);                              \
        GLDS16(srcB[0] + _ko, BsW + _bo);                                     \
        GLDS16(srcB[1] + _ko, BsW + _bo + 1024);                              \
    } while (0)

    int cur = 0;
    ESTG(0, 0);
    __syncthreads();
    for (int ks = 0; ks < 10; ++ks) {
        const int nxt = cur ^ 1;
        if (ks < 9) ESTG((ks + 1) * 64, nxt);
        short8 af[8], bfv[4];
        const char* Ac = As + cur * 16384;
        const char* Bc = Bs + cur * 16384;
#pragma unroll
        for (int m = 0; m < 8; ++m)
            af[m] = *(const short8*)(Ac + (wr * 128 + m * 16 + fm) * 64 + chunkOff);
#pragma unroll
        for (int n = 0; n < 4; ++n)
            bfv[n] = *(const short8*)(Bc + (wc * 64 + n * 16 + fm) * 64 + chunkOff);
        __builtin_amdgcn_s_setprio(1);
#pragma unroll
        for (int m = 0; m < 8; ++m)
#pragma unroll
            for (int n = 0; n < 4; ++n)
                acc[m][n] = __builtin_amdgcn_mfma_f32_16x16x32_bf16(
                    af[m], bfv[n], acc[m][n], 0, 0, 0);
        __builtin_amdgcn_s_setprio(0);
        __syncthreads();
        cur = nxt;
    }
#undef ESTG

#pragma unroll
    for (int m = 0; m < 8; ++m) {
        const int v = v0 + wr * 128 + m * 16 + ((lane >> 4) * 4);
#pragma unroll
        for (int n = 0; n < 4; ++n) {
            const int col = c0 + wc * 64 + n * 16 + fm;
#pragma unroll
            for (int r = 0; r < 4; ++r)
                *(ushort16*)(EC + (size_t)(v + r) * ECSTRIDE + col * 2) =
                    f2bf(acc[m][n][r]);
        }
    }
}

// ---------------------------------------------------------------------------
// gather_conv: out[b][l][f] = bf16( EC[t(l-1)][0*416+f] + EC[t(l)][1*416+f]
//                                 + EC[t(l+1)][2*416+f] + bias[f] )
// One thread per 16B chunk (52 chunks per row). Pure streaming, grid-stride.
// OOB positions use token 0 (EC row 0 is exactly zero: emb row 0 is zero).
// ---------------------------------------------------------------------------
__global__ __launch_bounds__(256) void gather_conv(
        const int* __restrict__ toks, const char* __restrict__ EC,
        const float* __restrict__ bias2, char* __restrict__ outb,
        int nb, int L)
{
    const int total = nb * L * 52;
    int id = blockIdx.x * 256 + threadIdx.x;
    const int stride = gridDim.x * 256;
    for (; id < total; id += stride) {
        const uint32 uid = (uint32)id;
        const int c = (int)(uid % 52u);
        const int r = (int)(uid / 52u);
        const int l = r & (L - 1), b = r / L;   // L is 512 or 128 (pow2)
        const int* tr = toks + (size_t)b * L;
        const int t0 = (l > 0)     ? tr[l - 1] : 0;
        const int t1 = tr[l];
        const int t2 = (l < L - 1) ? tr[l + 1] : 0;
        const uint4 x0 = *(const uint4*)(EC + (size_t)t0 * ECSTRIDE +        c * 16);
        const uint4 x1 = *(const uint4*)(EC + (size_t)t1 * ECSTRIDE +  832 + c * 16);
        const uint4 x2 = *(const uint4*)(EC + (size_t)t2 * ECSTRIDE + 1664 + c * 16);
        const float4 b0 = *(const float4*)(bias2 + c * 8);
        const float4 b1 = *(const float4*)(bias2 + c * 8 + 4);
        uint4 o;
        o.x = pack2(bf_lo(x0.x) + bf_lo(x1.x) + bf_lo(x2.x) + b0.x,
                    bf_hi(x0.x) + bf_hi(x1.x) + bf_hi(x2.x) + b0.y);
        o.y = pack2(bf_lo(x0.y) + bf_lo(x1.y) + bf_lo(x2.y) + b0.z,
                    bf_hi(x0.y) + bf_hi(x1.y) + bf_hi(x2.y) + b0.w);
        o.z = pack2(bf_lo(x0.z) + bf_lo(x1.z) + bf_lo(x2.z) + b1.x,
                    bf_hi(x0.z) + bf_hi(x1.z) + bf_hi(x2.z) + b1.y);
        o.w = pack2(bf_lo(x0.w) + bf_lo(x1.w) + bf_lo(x2.w) + b1.z,
                    bf_hi(x0.w) + bf_hi(x1.w) + bf_hi(x2.w) + b1.w);
        *(uint4*)(outb + (size_t)r * 832 + c * 16) = o;
    }
}

// ---------------------------------------------------------------------------
// qp_gemm: Qp[b] = Q[b] (128x416, biased) x Ub (416 cols) -> [128][416] bf16.
// Per batch 2 blocks (nt): nt0 cols 0..256 <2,4,4,4>, nt1 cols 256..416
// <4,2,2,5>. K=416 (13 steps). A rows 128 (8 waves x 16). 512 thr.
// ---------------------------------------------------------------------------
template<int NWM, int NWN, int MF, int NF, int BR>
static __device__ __forceinline__ void qp_tile(
        const char* __restrict__ Qb, const char* __restrict__ Ub,
        char* __restrict__ ob, int col0, char* As, char* Bs)
{
    const int t = threadIdx.x, lane = t & 63, w = t >> 6;
    const int wr = w / NWN, wc = w % NWN;
    const int fm = lane & 15;
    const int cg = ((lane & 3) - ((lane >> 3) & 3)) & 3;
    const int rl = lane >> 2;
    const int chunkOff = (((lane >> 4) + (fm >> 1)) & 3) * 16;

    const char* srcA = Qb + (size_t)(w * 16 + rl) * 832 + cg * 16;
    const char* srcB0; const char* srcB1 = 0;
    if (BR == 256) {
        srcB0 = Ub + (size_t)(col0 + w * 32 + rl) * 832 + cg * 16;
        srcB1 = srcB0 + (size_t)16 * 832;
    } else {
        srcB0 = Ub + (size_t)(col0 + w * 16 + rl) * 832 + cg * 16;
        srcB1 = Ub + (size_t)(col0 + 128 + w * 16 + rl) * 832 + cg * 16;
    }
    char* AsW = As + w * 1024;
    char* BsW0; char* BsW1;
    if (BR == 256) { BsW0 = Bs + w * 2048; BsW1 = BsW0 + 1024; }
    else           { BsW0 = Bs + w * 1024; BsW1 = Bs + 8192 + w * 1024; }
    const int BUFB = BR * 64;

    floatx4 acc[MF][NF];
    const floatx4 zz = {0.f, 0.f, 0.f, 0.f};
#pragma unroll
    for (int m = 0; m < MF; ++m)
#pragma unroll
        for (int n = 0; n < NF; ++n) acc[m][n] = zz;

#define QSTG(ko, buf) do {                                                    \
        const int _ko = (ko);                                                 \
        GLDS16(srcA + _ko, AsW + (buf) * 8192);                               \
        GLDS16(srcB0 + _ko, BsW0 + (buf) * BUFB);                             \
        if (BR == 256 || w < 2) GLDS16(srcB1 + _ko, BsW1 + (buf) * BUFB);     \
    } while (0)

    int cur = 0;
    QSTG(0, 0);
    __syncthreads();
    for (int ks = 0; ks < 13; ++ks) {
        const int nxt = cur ^ 1;
        if (ks < 12) QSTG((ks + 1) * 64, nxt);
        short8 af[MF], bfv[NF];
        const char* Ac = As + cur * 8192;
        const char* Bc = Bs + cur * BUFB;
#pragma unroll
        for (int m = 0; m < MF; ++m)
            af[m] = *(const short8*)(Ac + (wr * (MF * 16) + m * 16 + fm) * 64 + chunkOff);
#pragma unroll
        for (int n = 0; n < NF; ++n)
            bfv[n] = *(const short8*)(Bc + (wc * (NF * 16) + n * 16 + fm) * 64 + chunkOff);
        __builtin_amdgcn_s_setprio(1);
#pragma unroll
        for (int m = 0; m < MF; ++m)
#pragma unroll
            for (int n = 0; n < NF; ++n)
                acc[m][n] = __builtin_amdgcn_mfma_f32_16x16x32_bf16(
                    af[m], bfv[n], acc[m][n], 0, 0, 0);
        __builtin_amdgcn_s_setprio(0);
        __syncthreads();
        cur = nxt;
    }
#undef QSTG

#pragma unroll
    for (int m = 0; m < MF; ++m) {
        const int row = wr * (MF * 16) + m * 16 + ((lane >> 4) * 4);
#pragma unroll
        for (int n = 0; n < NF; ++n) {
            const int col = col0 + wc * (NF * 16) + n * 16 + fm;
#pragma unroll
            for (int r = 0; r < 4; ++r)
                *(ushort16*)(ob + (size_t)(row + r) * 832 + col * 2) =
                    f2bf(acc[m][n][r]);
        }
    }
}

__global__ __launch_bounds__(512) void qp_gemm(
        const char* __restrict__ qb, const char* __restrict__ Ub,
        char* __restrict__ qpb)
{
    __shared__ __align__(16) char As[16384];   // 2 x 128 x 64B
    __shared__ __align__(16) char Bs[32768];   // 2 x <=256 x 64B
    const int bx = blockIdx.x;
    const int b = bx >> 1, nt = bx & 1;
    const char* Qb = qb + (size_t)b * 106496;
    char* ob = qpb + (size_t)b * 106496;
    if (nt == 0)
        qp_tile<2, 4, 4, 4, 256>(Qb, Ub, ob, 0, As, Bs);
    else
        qp_tile<4, 2, 2, 5, 160>(Qb, Ub, ob, 256, As, Bs);
}

// ---------------------------------------------------------------------------
// fused_g: block (b, a-chunk c). Gpre = Qp A^T (K=416, cols 400..416 zeros).
// Double-buffered 2-phase pipeline, single barrier per K-step. (unchanged)
// ---------------------------------------------------------------------------
__global__ __launch_bounds__(256) void fused_g(
        const ushort16* __restrict__ Qp,   // [nb][128][416]
        const ushort16* __restrict__ Av,   // [nb][512][416]
        float* __restrict__ rowPart,       // [nb][4][128]
        float* __restrict__ colMg,         // [nb][512]
        int nb)
{
    __shared__ __align__(16) char Qs[16384];    // 2 x 8192 (dbuf)
    __shared__ __align__(16) char Asl[16384];   // 2 x 8192 (dbuf)
    __shared__ float rowM2[128][2];
    __shared__ float colM2[128][2];

    const int t = threadIdx.x, lane = t & 63, w = t >> 6;
    const int bx = blockIdx.x;
    const int xcd = bx & 7, rest = bx >> 3;
    const int c = rest & 3, g = rest >> 2;
    const int T = g * 8 + xcd;
    if (T >= nb) return;
    const int b = T;
    const int wr = w >> 1, wc = w & 1;
    const int fm = lane & 15;
    const int cg = ((lane & 3) - ((lane >> 3) & 3)) & 3;
    const int srow = w * 16 + (lane >> 2);
    const int chunkOff = (((lane >> 4) + (fm >> 1)) & 3) * 16;

    const char* Qpb = (const char*)Qp + (size_t)b * 106496;
    const char* Ab  = (const char*)Av + (size_t)b * 425984 + (size_t)c * 106496;
    const char* srcQ = Qpb + (size_t)srow * 832 + cg * 16;
    const char* srcA = Ab  + (size_t)srow * 832 + cg * 16;
    char* QsW = Qs + w * 1024;
    char* AsW = Asl + w * 1024;

    floatx4 acc[4][4];
    const floatx4 zz = {0.f, 0.f, 0.f, 0.f};
#pragma unroll
    for (int m = 0; m < 4; ++m)
#pragma unroll
        for (int n = 0; n < 4; ++n) acc[m][n] = zz;

#define GSTAGE(colb, buf) do {                                                \
        const int _c = (colb); const int _o = (buf) * 8192;                   \
        GLDS16(srcQ + _c,         QsW + _o);                                  \
        GLDS16(srcQ + 53248 + _c, QsW + _o + 4096);                           \
        GLDS16(srcA + _c,         AsW + _o);                                  \
        GLDS16(srcA + 53248 + _c, AsW + _o + 4096);                           \
    } while (0)

    int cur = 0;
    GSTAGE(0, 0);
    __syncthreads();

    for (int ks = 0; ks < 13; ++ks) {
        const int nxt = cur ^ 1;
        if (ks < 12) GSTAGE((ks + 1) * 64, nxt);

        short8 qa[4], aa_[4];
        const char* Qc = Qs + cur * 8192;
        const char* Ac = Asl + cur * 8192;
#pragma unroll
        for (int m = 0; m < 4; ++m)
            qa[m] = *(const short8*)(Qc + (wr * 64 + m * 16 + fm) * 64 + chunkOff);
#pragma unroll
        for (int n = 0; n < 4; ++n)
            aa_[n] = *(const short8*)(Ac + (wc * 64 + n * 16 + fm) * 64 + chunkOff);
        __builtin_amdgcn_s_setprio(1);
#pragma unroll
        for (int m = 0; m < 4; ++m)
#pragma unroll
            for (int n = 0; n < 4; ++n)
                acc[m][n] = __builtin_amdgcn_mfma_f32_16x16x32_bf16(
                    qa[m], aa_[n], acc[m][n], 0, 0, 0);
        __builtin_amdgcn_s_setprio(0);
        __syncthreads();
        cur = nxt;
    }
#undef GSTAGE

#pragma unroll
    for (int m = 0; m < 4; ++m)
#pragma unroll
        for (int r = 0; r < 4; ++r) {
            float v = fmaxf(fmaxf(acc[m][0][r], acc[m][1][r]),
                            fmaxf(acc[m][2][r], acc[m][3][r]));
            v = fmaxf(v, __shfl_xor(v, 1));
            v = fmaxf(v, __shfl_xor(v, 2));
            v = fmaxf(v, __shfl_xor(v, 4));
            v = fmaxf(v, __shfl_xor(v, 8));
            if (fm == 0) rowM2[wr * 64 + m * 16 + (lane >> 4) * 4 + r][wc] = v;
        }
#pragma unroll
    for (int n = 0; n < 4; ++n) {
        float v = -1e30f;
#pragma unroll
        for (int m = 0; m < 4; ++m)
#pragma unroll
            for (int r = 0; r < 4; ++r) v = fmaxf(v, acc[m][n][r]);
        v = fmaxf(v, __shfl_xor(v, 16));
        v = fmaxf(v, __shfl_xor(v, 32));
        if (lane < 16) colM2[wc * 64 + n * 16 + lane][wr] = v;
    }
    __syncthreads();
    if (t < 128) {
        rowPart[((size_t)b * 4 + c) * 128 + t] = fmaxf(rowM2[t][0], rowM2[t][1]);
        colMg[(size_t)b * 512 + c * 128 + t]   = fmaxf(colM2[t][0], colM2[t][1]);
    }
}

// ---------------------------------------------------------------------------
// fused_pool: per-batch softmax over tanh(maxes) + pooling + cosine.
// ---------------------------------------------------------------------------
static __device__ __forceinline__ float block_reduce_max(float v, volatile float* red) {
    int t = threadIdx.x;
    red[t] = v; __syncthreads();
    for (int s = 128; s > 0; s >>= 1) {
        if (t < s) red[t] = fmaxf(red[t], red[t + s]);
        __syncthreads();
    }
    float r = red[0]; __syncthreads();
    return r;
}
static __device__ __forceinline__ float block_reduce_sum(float v, volatile float* red) {
    int t = threadIdx.x;
    red[t] = v; __syncthreads();
    for (int s = 128; s > 0; s >>= 1) {
        if (t < s) red[t] = red[t] + red[t + s];
        __syncthreads();
    }
    float r = red[0]; __syncthreads();
    return r;
}

__global__ __launch_bounds__(256) void fused_pool(
        const ushort16* __restrict__ Qv,   // [nb][128][416]
        const ushort16* __restrict__ Av,   // [nb][512][416]
        const float* __restrict__ rowPart, // [nb][4][128]
        const float* __restrict__ colMg,   // [nb][512]
        float* __restrict__ out)
{
    __shared__ float colv[ALn];
    __shared__ float roq[QLn];
    __shared__ float red[256];
    const int t = threadIdx.x, b = blockIdx.x;

    float v = -1e30f;
    if (t < QLn) {
        const float* rp = rowPart + (size_t)b * 512;
        float rm = fmaxf(fmaxf(rp[t], rp[128 + t]), fmaxf(rp[256 + t], rp[384 + t]));
        v = tanhf(rm);
    }
    float vmax = block_reduce_max(v, red);
    float ex = (t < QLn) ? __expf(v - vmax) : 0.f;
    float ssum = block_reduce_sum(ex, red);
    if (t < QLn) roq[t] = ex / ssum;

    float c0 = tanhf(colMg[(size_t)b * 512 + t]);
    float c1 = tanhf(colMg[(size_t)b * 512 + 256 + t]);
    float cmax = block_reduce_max(fmaxf(c0, c1), red);
    float e0 = __expf(c0 - cmax), e1 = __expf(c1 - cmax);
    float csum = block_reduce_sum(e0 + e1, red);
    colv[t] = e0 / csum;
    colv[t + 256] = e1 / csum;
    __syncthreads();

    float rq0 = 0.f, rq1 = 0.f, ra0 = 0.f, ra1 = 0.f;
    if (t < 208) {
        const uint32* Qb32 = (const uint32*)((const char*)Qv + (size_t)b * 106496);
#pragma unroll 4
        for (int q = 0; q < QLn; ++q) {
            float wv = roq[q];
            uint32 u = Qb32[q * 208 + t];
            rq0 = fmaf(bf_lo(u), wv, rq0);
            rq1 = fmaf(bf_hi(u), wv, rq1);
        }
        const uint32* Ab32 = (const uint32*)((const char*)Av + (size_t)b * 425984);
#pragma unroll 4
        for (int a = 0; a < ALn; ++a) {
            float wv = colv[a];
            uint32 u = Ab32[a * 208 + t];
            ra0 = fmaf(bf_lo(u), wv, ra0);
            ra1 = fmaf(bf_hi(u), wv, ra1);
        }
    }

    float dd  = block_reduce_sum(rq0 * ra0 + rq1 * ra1, red);
    float qq  = block_reduce_sum(rq0 * rq0 + rq1 * rq1, red);
    float aam = block_reduce_sum(ra0 * ra0 + ra1 * ra1, red);
    if (t == 0) {
        float nq = fmaxf(sqrtf(qq), 1e-8f);
        float na = fmaxf(sqrtf(aam), 1e-8f);
        out[b] = dd / (nq * na);
    }
}

// ---------------------------------------------------------------------------
// launch — ws: [Wt2 | bias2 | Ub | EC | overlay{embbf | per-chunk bufs}]
// embbf is only needed to build EC; per-chunk buffers overlay it afterwards.
// ---------------------------------------------------------------------------
extern "C" void kernel_launch(void* const* d_in, const int* in_sizes, int n_in,
                              void* d_out, int out_size, void* d_ws, size_t ws_size,
                              hipStream_t stream)
{
    const int*   question = (const int*)d_in[0];
    const int*   answer   = (const int*)d_in[1];
    const float* emb      = (const float*)d_in[2];
    const float* conv_w   = (const float*)d_in[3];
    const float* conv_b   = (const float*)d_in[4];
    const float* U        = (const float*)d_in[5];
    float* out = (float*)d_out;
    char* ws = (char*)d_ws;

    const size_t WT2B   = (size_t)512 * 960 * 2;             // 983,040
    const size_t UBB    = (size_t)416 * 416 * 2;             // 346,112
    const size_t ECB    = (size_t)ECROWS * ECSTRIDE;         // 128,450,560
    const size_t FIXED0 = WT2B + 2048 + UBB + ECB;           // 129,781,760
    const size_t QB     = (size_t)QLn * OW * 2;              // 106,496
    const size_t AB     = (size_t)ALn * OW * 2;              // 425,984
    const size_t MXB    = 4096;
    const size_t PER_B  = 2 * QB + AB + MXB;                 // 643,072

    size_t avail = (ws_size > FIXED0) ? (ws_size - FIXED0) : 0;
    int CB = (int)(avail / PER_B);
    if (CB > Bb) CB = Bb;
    if (CB < 1)  CB = 1;
    int nch = (Bb + CB - 1) / CB;
    int CBe = (Bb + nch - 1) / nch;      // balanced chunk size (<= CB)

    char*  wt2   = ws;
    float* bias2 = (float*)(ws + WT2B);
    char*  ub    = ws + WT2B + 2048;
    char*  EC    = ws + WT2B + 2048 + UBB;
    char*  embbf = ws + FIXED0;           // overlay: used only for ec_gemm
    char*  qb    = ws + FIXED0;           // overlay after ec_gemm completes
    char*  qpb   = qb  + (size_t)CB * QB;
    char*  ab    = qpb + (size_t)CB * QB;
    float* rowP  = (float*)(ab + (size_t)CB * AB);
    float* colM  = rowP + (size_t)CB * 512;

    embcvt_kernel<<<NV, 128, 0, stream>>>(emb, embbf);
    prep_wt<<<512, 256, 0, stream>>>(conv_w, conv_b, (ushort16*)wt2, bias2);
    prep_ub<<<416, 256, 0, stream>>>(U, (ushort16*)ub);
    ec_gemm<<<dim3(196, 5), 512, 0, stream>>>(embbf, wt2, EC);

    for (int b0 = 0; b0 < Bb; b0 += CBe) {
        int nb = (Bb - b0 < CBe) ? (Bb - b0) : CBe;
        gather_conv<<<1024, 256, 0, stream>>>(
            question + (size_t)b0 * QLn, EC, bias2, qb, nb, QLn);
        gather_conv<<<4096, 256, 0, stream>>>(
            answer + (size_t)b0 * ALn, EC, bias2, ab, nb, ALn);
        qp_gemm<<<nb * 2, 512, 0, stream>>>(qb, ub, qpb);

        int blocksG = ((nb + 7) / 8) * 8 * 4;
        fused_g<<<blocksG, 256, 0, stream>>>((const ushort16*)qpb, (const ushort16*)ab,
                                             rowP, colM, nb);
        fused_pool<<<nb, 256, 0, stream>>>((const ushort16*)qb, (const ushort16*)ab,
                                           rowP, colM, out + b0);
    }
}